// Round 6
// baseline (1036.483 us; speedup 1.0000x reference)
//
#include <hip/hip_runtime.h>
#include <hip/hip_bf16.h>

typedef __attribute__((ext_vector_type(8))) short bf16x8;
typedef __attribute__((ext_vector_type(4))) float f32x4;

// ---------------------------------------------------------------- pool: xbar[b][c][t] = mean_hw x
__global__ __launch_bounds__(256) void pool_kernel(const float* __restrict__ x,
                                                   float* __restrict__ xbar) {
    int row = blockIdx.x * 16 + (threadIdx.x >> 4);   // (b*1024+c)*8+t
    int j = threadIdx.x & 15;
    const float4* p = (const float4*)(x + (size_t)row * 128);
    float4 a = p[j * 2], b2 = p[j * 2 + 1];
    float s = a.x + a.y + a.z + a.w + b2.x + b2.y + b2.z + b2.w;
    s += __shfl_xor(s, 1); s += __shfl_xor(s, 2);
    s += __shfl_xor(s, 4); s += __shfl_xor(s, 8);
    if (j == 0) xbar[row] = s * (1.0f / 128.0f);
}

// ------------------------------------------- theta/phi: [b][ic][t] = W @ xbar[b][:][t] + bias
__global__ __launch_bounds__(256) void thetaphi_kernel(
        const float* __restrict__ xbar,
        const float* __restrict__ tw, const float* __restrict__ tb,
        const float* __restrict__ pw, const float* __restrict__ pb,
        float* __restrict__ theta, float* __restrict__ phi) {
    int which = blockIdx.x & 1;
    int icc = (blockIdx.x >> 1) & 15;
    int b = blockIdx.x >> 5;
    const float* w = which ? pw : tw;
    const float* bias = which ? pb : tb;
    float* out = which ? phi : theta;
    __shared__ float xs[8192];
    for (int i = threadIdx.x; i < 8192; i += 256) xs[i] = xbar[b * 8192 + i];
    __syncthreads();
    int icl = threadIdx.x >> 3;
    int t = threadIdx.x & 7;
    int ic = icc * 32 + icl;
    const float* wr = w + (size_t)ic * 1024;
    float acc = 0.0f;
    #pragma unroll 8
    for (int k = 0; k < 1024; k++) acc += wr[k] * xs[k * 8 + t];
    out[((size_t)b * 512 + ic) * 8 + t] = acc + bias[ic];
}

// ------------------------------------------------------- attn[b][t][s] = softmax_s(theta.phi)
__global__ __launch_bounds__(64) void attn_kernel(const float* __restrict__ theta,
                                                  const float* __restrict__ phi,
                                                  float* __restrict__ attn) {
    __shared__ float th[4096], ph[4096];
    int b = blockIdx.x, lane = threadIdx.x;
    for (int i = lane; i < 4096; i += 64) {
        th[i] = theta[(size_t)b * 4096 + i];
        ph[i] = phi[(size_t)b * 4096 + i];
    }
    __syncthreads();
    int t = lane >> 3, s = lane & 7;
    float f = 0.0f;
    #pragma unroll 8
    for (int ic = 0; ic < 512; ic++) f += th[ic * 8 + t] * ph[ic * 8 + s];
    float m = f;
    m = fmaxf(m, __shfl_xor(m, 1));
    m = fmaxf(m, __shfl_xor(m, 2));
    m = fmaxf(m, __shfl_xor(m, 4));
    float e = __expf(f - m);
    float sum = e;
    sum += __shfl_xor(sum, 1); sum += __shfl_xor(sum, 2); sum += __shfl_xor(sum, 4);
    attn[b * 64 + lane] = e / sum;
}

// --------------------------- prep: gwt[cin][ic] = bf16(g_w[ic][cin]); wwb = bf16(w_w)
__global__ __launch_bounds__(256) void prep_operands_kernel(
        const float* __restrict__ gw, const float* __restrict__ ww,
        __hip_bfloat16* __restrict__ gwt, __hip_bfloat16* __restrict__ wwb) {
    int bid = blockIdx.x;
    if (bid < 512) {
        int icb = bid >> 5;            // 0..15
        int cb = bid & 31;             // 0..31
        __shared__ float tile[32][33];
        int r = threadIdx.x >> 5, c = threadIdx.x & 31;   // 8 x 32
        #pragma unroll
        for (int i = 0; i < 4; i++)
            tile[r + i * 8][c] = gw[(size_t)(icb * 32 + r + i * 8) * 1024 + cb * 32 + c];
        __syncthreads();
        #pragma unroll
        for (int i = 0; i < 4; i++) {
            int cin = cb * 32 + r + i * 8;
            gwt[(size_t)cin * 512 + icb * 32 + c] = __float2bfloat16(tile[c][r + i * 8]);
        }
    } else {
        int b2 = bid - 512;
        size_t base = (size_t)b2 * 2048 + (size_t)threadIdx.x * 8;
        const float4* src = (const float4*)(ww + base);
        float4 v0 = src[0], v1 = src[1];
        __hip_bfloat16 tmp[8];
        tmp[0] = __float2bfloat16(v0.x); tmp[1] = __float2bfloat16(v0.y);
        tmp[2] = __float2bfloat16(v0.z); tmp[3] = __float2bfloat16(v0.w);
        tmp[4] = __float2bfloat16(v1.x); tmp[5] = __float2bfloat16(v1.y);
        tmp[6] = __float2bfloat16(v1.z); tmp[7] = __float2bfloat16(v1.w);
        *(bf16x8*)(wwb + base) = *(const bf16x8*)tmp;
    }
}

#if defined(__has_builtin)
#if __has_builtin(__builtin_amdgcn_global_load_lds)
#define USE_GLOAD_LDS 1
#endif
#endif

__device__ __forceinline__ void gload_lds16(const void* g, void* ldsbase) {
#ifdef USE_GLOAD_LDS
    __builtin_amdgcn_global_load_lds(
        (__attribute__((address_space(1))) void*)(g),
        (__attribute__((address_space(3))) void*)(ldsbase), 16, 0, 0);
#endif
}

// --------------------------- prepM via MFMA: M[c][cin] = sum_k wwb[c][k]*gwt[cin][k]
__global__ __launch_bounds__(256) void prepM_mfma_kernel(
        const __hip_bfloat16* __restrict__ wwb,   // [1024][512]
        const __hip_bfloat16* __restrict__ gwt,   // [1024][512]
        __hip_bfloat16* __restrict__ M) {
    __shared__ __align__(16) __hip_bfloat16 As[128 * 32];
    __shared__ __align__(16) __hip_bfloat16 Bs[128 * 32];
    int bid = blockIdx.x;
    int mb = bid >> 3, nb = bid & 7;
    int c0 = mb * 128, n0 = nb * 128;
    int tid = threadIdx.x;
    int w = tid >> 6, l = tid & 63;
    int wr = w >> 1, wc = w & 1;
    const __hip_bfloat16* Ab = wwb + (size_t)c0 * 512;
    const __hip_bfloat16* Bb = gwt + (size_t)n0 * 512;
    int arow = tid >> 2, akq = tid & 3;
    f32x4 acc[4][4] = {};

    for (int kk = 0; kk < 16; ++kk) {
        int k0 = kk * 32;
#ifdef USE_GLOAD_LDS
        gload_lds16(Ab + (size_t)arow * 512 + k0 + akq * 8,        (char*)As + w * 1024);
        gload_lds16(Ab + (size_t)(arow + 64) * 512 + k0 + akq * 8, (char*)As + 4096 + w * 1024);
        gload_lds16(Bb + (size_t)arow * 512 + k0 + akq * 8,        (char*)Bs + w * 1024);
        gload_lds16(Bb + (size_t)(arow + 64) * 512 + k0 + akq * 8, (char*)Bs + 4096 + w * 1024);
#else
        *(bf16x8*)((char*)As + (size_t)tid * 16)        = *(const bf16x8*)(Ab + (size_t)arow * 512 + k0 + akq * 8);
        *(bf16x8*)((char*)As + 4096 + (size_t)tid * 16) = *(const bf16x8*)(Ab + (size_t)(arow + 64) * 512 + k0 + akq * 8);
        *(bf16x8*)((char*)Bs + (size_t)tid * 16)        = *(const bf16x8*)(Bb + (size_t)arow * 512 + k0 + akq * 8);
        *(bf16x8*)((char*)Bs + 4096 + (size_t)tid * 16) = *(const bf16x8*)(Bb + (size_t)(arow + 64) * 512 + k0 + akq * 8);
#endif
        __syncthreads();
        const __hip_bfloat16* Ap = As + ((size_t)(wr * 64 + (l & 15)) * 32) + (l >> 4) * 8;
        const __hip_bfloat16* Bp = Bs + ((size_t)(wc * 64 + (l & 15)) * 32) + (l >> 4) * 8;
        bf16x8 af[4], bfr[4];
        #pragma unroll
        for (int m = 0; m < 4; m++) af[m] = *(const bf16x8*)(Ap + m * 16 * 32);
        #pragma unroll
        for (int n = 0; n < 4; n++) bfr[n] = *(const bf16x8*)(Bp + n * 16 * 32);
        #pragma unroll
        for (int m = 0; m < 4; m++)
            #pragma unroll
            for (int n = 0; n < 4; n++)
                acc[m][n] = __builtin_amdgcn_mfma_f32_16x16x32_bf16(af[m], bfr[n], acc[m][n], 0, 0, 0);
        __syncthreads();
    }

    int col = l & 15, rg = l >> 4;
    #pragma unroll
    for (int m = 0; m < 4; m++)
        #pragma unroll
        for (int j = 0; j < 4; j++) {
            int gc = c0 + wr * 64 + m * 16 + rg * 4 + j;
            #pragma unroll
            for (int n = 0; n < 4; n++)
                M[(size_t)gc * 1024 + n0 + wc * 64 + n * 16 + col] = __float2bfloat16(acc[m][n][j]);
        }
}

// ---------------- per-channel epilogue constants inv[c], shift[c] (wave-parallel dot)
__global__ __launch_bounds__(256) void prepbias_kernel(
        const float* __restrict__ ww, const float* __restrict__ gb,
        const float* __restrict__ wb, const float* __restrict__ gamma,
        const float* __restrict__ beta, const float* __restrict__ mean,
        const float* __restrict__ var, float* __restrict__ inv,
        float* __restrict__ shift) {
    int wv = threadIdx.x >> 6, l = threadIdx.x & 63;
    int c = blockIdx.x * 32 + wv * 8 + (l >> 3);   // 32 blocks x 32 channels
    int j = l & 7;
    const float* wr = ww + (size_t)c * 512;
    float acc = 0.0f;
    #pragma unroll 8
    for (int k = j; k < 512; k += 8) acc += wr[k] * gb[k];
    acc += __shfl_xor(acc, 1); acc += __shfl_xor(acc, 2); acc += __shfl_xor(acc, 4);
    if (j == 0) {
        float cb = wb[c] + acc;
        float iv = gamma[c] * rsqrtf(var[c] + 1e-5f);
        inv[c] = iv;
        shift[c] = cb * iv + beta[c] - mean[c] * iv;
    }
}

// ------------- mix + transpose: xm_t[b][t*128+hw][c] (bf16) = sum_s attn[b][t][s]*x[b][c][s][hw]
__global__ __launch_bounds__(256) void mix_kernel(const float* __restrict__ x,
                                                  const float* __restrict__ attn,
                                                  __hip_bfloat16* __restrict__ xmt) {
    int orig = blockIdx.x;
    int wg = (orig & 7) * 64 + (orig >> 3);
    int b = wg >> 4;
    int hwg = wg & 15;                          // group of 8 hw positions
    __shared__ float at[64];
    __shared__ float xs[8][8][33];              // [s][h][ci], ci-dim padded to 33
    int tid = threadIdx.x;
    if (tid < 64) at[tid] = attn[b * 64 + tid];
    int ci = tid >> 3, s = tid & 7;             // staging role: 32 c x 8 s
    int h = tid >> 5, cq = tid & 31;            // compute role: 8 h x 32 c
    const float* xb = x + ((size_t)b << 20);
    __hip_bfloat16* ob = xmt + ((size_t)b << 20);
    for (int cc = 0; cc < 32; ++cc) {
        const float4* src = (const float4*)(xb + ((size_t)(cc * 32 + ci) * 8 + s) * 128 + hwg * 8);
        float4 v0 = src[0], v1 = src[1];
        __syncthreads();
        xs[s][0][ci] = v0.x; xs[s][1][ci] = v0.y; xs[s][2][ci] = v0.z; xs[s][3][ci] = v0.w;
        xs[s][4][ci] = v1.x; xs[s][5][ci] = v1.y; xs[s][6][ci] = v1.z; xs[s][7][ci] = v1.w;
        __syncthreads();
        float xr[8];
        #pragma unroll
        for (int ss = 0; ss < 8; ss++) xr[ss] = xs[ss][h][cq];
        #pragma unroll
        for (int t = 0; t < 8; t++) {
            float o = 0.0f;
            #pragma unroll
            for (int ss = 0; ss < 8; ss++) o += at[t * 8 + ss] * xr[ss];
            ob[(size_t)(t * 128 + hwg * 8 + h) * 1024 + cc * 32 + cq] = __float2bfloat16(o);
        }
    }
}

// ========== 256x256-tile / 8-wave GEMM, half-K(32) pipeline, 2 blocks/CU (64 KiB LDS) =========
// out[b][c][n] = inv[c] * sum_k M[c][k]*xmt[b][n][k] + shift[c] + x[b][c][n]
// LDS: 2 half-buffers x (A 256x32 + B 256x32) bf16 = 64 KiB -> 2 blocks/CU, 16 waves/CU.
// Step h (buf q=h&1): {12 ds_read(q) -> lgkmcnt(0) -> s_barrier -> ISSUE refill(q, data h+2)
//  -> 32 MFMA w/ setprio -> vmcnt(4) -> s_barrier}. Refill issued right after all waves
// finish READING q (same-slot reuse safe), lands ~1.5-2 steps later (counted vmcnt, T4).
// Swizzle: slot' = (slot + (row>>1)) & 3 within each 64B row, both-sides (rule #21).
__global__ __launch_bounds__(512, 4) void gemm256_kernel(
        const __hip_bfloat16* __restrict__ Mw,    // [1024][1024]  (c, k)
        const __hip_bfloat16* __restrict__ xmt,   // [32][1024][1024] (n, k)
        const float* __restrict__ x,              // [32][1024][1024] (c, n)
        const float* __restrict__ inv, const float* __restrict__ shift,
        float* __restrict__ out) {
    __shared__ __align__(16) __hip_bfloat16 HBs[32768];        // 64 KiB = 2 x 32 KiB
    char* AH = (char*)HBs;
    const int BUFB = 32768;                                    // bytes per half-buffer

    int orig = blockIdx.x;
    int bid = (orig & 7) * 64 + (orig >> 3);      // XCD-chunked swizzle (512 % 8 == 0)
    int b = bid >> 4;
    int mb = (bid >> 2) & 3;
    int nb = bid & 3;
    int c0 = mb * 256, n0 = nb * 256;

    int tid = threadIdx.x;
    int w = tid >> 6, l = tid & 63;
    int wr = w >> 2, wc = w & 3;                  // 2 x 4 wave grid; wave out = 128(M) x 64(N)

    // ---- staging: lane l covers row w*16 + (l>>2), linear LDS slot l&3,
    //      global slot s = ((l&3) - ((l>>3)&3)) & 3  (inverse of slot' = (s + (row>>1))&3)
    int sgl = (((l & 3) - ((l >> 3) & 3)) & 3);
    const __hip_bfloat16* aS = Mw + (size_t)(c0 + w * 16 + (l >> 2)) * 1024 + sgl * 8;
    const __hip_bfloat16* bS = xmt + ((size_t)b << 20) + (size_t)(n0 + w * 16 + (l >> 2)) * 1024 + sgl * 8;
    int stBase = w * 1024;                        // byte base within half-region (wave slab)

    // ---- ds_read: slot = ((l>>4) + (((l&15)>>1)&3)) & 3, fragment adds 1024B (16 rows)
    int rdSlot = ((l >> 4) + (((l & 15) >> 1) & 3)) & 3;
    int aRdBase = (wr * 128 + (l & 15)) * 64 + rdSlot * 16;
    int bRdBase = 16384 + (wc * 64 + (l & 15)) * 64 + rdSlot * 16;

    f32x4 acc[8][4] = {};

    #define ISSUE(q) do {                                                       \
        gload_lds16(aS,              AH + (q) * BUFB + stBase);                 \
        gload_lds16(aS + 128 * 1024, AH + (q) * BUFB + stBase + 8192);          \
        gload_lds16(bS,              AH + (q) * BUFB + 16384 + stBase);         \
        gload_lds16(bS + 128 * 1024, AH + (q) * BUFB + 16384 + stBase + 8192);  \
        aS += 32; bS += 32;                                                     \
    } while (0)

    #define LGKM0 do { asm volatile("s_waitcnt lgkmcnt(0)" ::: "memory");       \
                       __builtin_amdgcn_sched_barrier(0); } while (0)
    #define V4 asm volatile("s_waitcnt vmcnt(4)" ::: "memory")
    #define V0 asm volatile("s_waitcnt vmcnt(0)" ::: "memory")

    // MODE: 0 = refill + vmcnt(4), 1 = no refill + vmcnt(0), 2 = last (no sync)
    #define HSTEP(q, MODE) do {                                                 \
        const char* bufA = AH + (q) * BUFB;                                     \
        bf16x8 bfr[4];                                                          \
        _Pragma("unroll")                                                       \
        for (int n = 0; n < 4; ++n)                                             \
            bfr[n] = *(const bf16x8*)(bufA + bRdBase + n * 1024);               \
        bf16x8 af[8];                                                           \
        _Pragma("unroll")                                                       \
        for (int mi = 0; mi < 8; ++mi)                                          \
            af[mi] = *(const bf16x8*)(bufA + aRdBase + mi * 1024);              \
        LGKM0;                                                                  \
        __builtin_amdgcn_s_barrier();       /* all waves done reading q */      \
        __builtin_amdgcn_sched_barrier(0);                                      \
        if ((MODE) == 0) ISSUE(q);          /* refill q with data for h+2 */    \
        __builtin_amdgcn_sched_barrier(0);                                      \
        __builtin_amdgcn_s_setprio(1);                                          \
        _Pragma("unroll")                                                       \
        for (int mi = 0; mi < 8; ++mi)                                          \
            _Pragma("unroll")                                                   \
            for (int n = 0; n < 4; ++n)                                         \
                acc[mi][n] = __builtin_amdgcn_mfma_f32_16x16x32_bf16(           \
                    af[mi], bfr[n], acc[mi][n], 0, 0, 0);                       \
        __builtin_amdgcn_s_setprio(0);                                          \
        if ((MODE) == 0) { V4; }                                                \
        else if ((MODE) == 1) { V0; }                                           \
        if ((MODE) != 2) {                                                      \
            __builtin_amdgcn_s_barrier();                                       \
            __builtin_amdgcn_sched_barrier(0);                                  \
        }                                                                       \
    } while (0)

    // prologue: issue halves 0,1 into bufs 0,1 (8 loads/thread)
    ISSUE(0); ISSUE(1);
    V4;                                           // half 0 landed (4 = half 1 in flight)
    __builtin_amdgcn_s_barrier();
    __builtin_amdgcn_sched_barrier(0);

    // main: 32 half-steps; steps 0..29 refill, 30 drains, 31 bare
    #pragma unroll 1
    for (int t = 0; t < 15; ++t) {
        HSTEP(0, 0);
        HSTEP(1, 0);
    }
    HSTEP(0, 1);           // h=30: no refill, vmcnt(0) waits h=31's data
    HSTEP(1, 2);           // h=31

    #undef ISSUE
    #undef HSTEP
    #undef LGKM0
    #undef V4
    #undef V0

    // epilogue: C/D layout col = l&15, row = (l>>4)*4 + j
    int col = l & 15, rg = l >> 4;
    const float* xb = x + ((size_t)b << 20);
    float* ob = out + ((size_t)b << 20);
    #pragma unroll
    for (int mi = 0; mi < 8; ++mi) {
        #pragma unroll
        for (int j = 0; j < 4; ++j) {
            int gc = c0 + wr * 128 + mi * 16 + rg * 4 + j;
            float iv = inv[gc], sh = shift[gc];
            size_t rowoff = (size_t)gc * 1024 + n0 + wc * 64 + col;
            #pragma unroll
            for (int n = 0; n < 4; ++n) {
                size_t idx = rowoff + n * 16;
                ob[idx] = acc[mi][n][j] * iv + sh + xb[idx];
            }
        }
    }
}

extern "C" void kernel_launch(void* const* d_in, const int* in_sizes, int n_in,
                              void* d_out, int out_size, void* d_ws, size_t ws_size,
                              hipStream_t stream) {
    const float* x    = (const float*)d_in[0];
    const float* g_w  = (const float*)d_in[1];
    const float* g_b  = (const float*)d_in[2];
    const float* th_w = (const float*)d_in[3];
    const float* th_b = (const float*)d_in[4];
    const float* ph_w = (const float*)d_in[5];
    const float* ph_b = (const float*)d_in[6];
    const float* w_w  = (const float*)d_in[7];
    const float* w_b  = (const float*)d_in[8];
    const float* gam  = (const float*)d_in[9];
    const float* bet  = (const float*)d_in[10];
    const float* mea  = (const float*)d_in[11];
    const float* var  = (const float*)d_in[12];
    float* out = (float*)d_out;
    char* ws = (char*)d_ws;

    __hip_bfloat16* xmt = (__hip_bfloat16*)ws;                    // 64 MiB (written by mix, late)
    __hip_bfloat16* Mw  = (__hip_bfloat16*)(ws + 67108864);       // 2 MiB
    float* xbar  = (float*)(ws + 69206016);                       // 1 MiB
    float* theta = (float*)(ws + 70254592);                       // 512 KiB
    float* phi   = (float*)(ws + 70778880);                       // 512 KiB
    float* attn  = (float*)(ws + 71303168);                       // 8 KiB
    float* inv   = (float*)(ws + 71311360);                       // 4 KiB
    float* shift = (float*)(ws + 71315456);                       // 4 KiB
    // gwt/wwb overlay the xmt region: consumed by prepM_mfma BEFORE mix writes xmt
    __hip_bfloat16* gwt = (__hip_bfloat16*)ws;                    // 1 MiB
    __hip_bfloat16* wwb = (__hip_bfloat16*)(ws + 1048576);        // 1 MiB

    hipLaunchKernelGGL(pool_kernel, dim3(16384), dim3(256), 0, stream, x, xbar);
    hipLaunchKernelGGL(thetaphi_kernel, dim3(1024), dim3(256), 0, stream,
                       xbar, th_w, th_b, ph_w, ph_b, theta, phi);
    hipLaunchKernelGGL(attn_kernel, dim3(32), dim3(64), 0, stream, theta, phi, attn);
    hipLaunchKernelGGL(prep_operands_kernel, dim3(768), dim3(256), 0, stream,
                       g_w, w_w, gwt, wwb);
    hipLaunchKernelGGL(prepM_mfma_kernel, dim3(64), dim3(256), 0, stream, wwb, gwt, Mw);
    hipLaunchKernelGGL(prepbias_kernel, dim3(32), dim3(256), 0, stream,
                       w_w, g_b, w_b, gam, bet, mea, var, inv, shift);
    hipLaunchKernelGGL(mix_kernel, dim3(512), dim3(256), 0, stream, x, attn, xmt);
    hipLaunchKernelGGL(gemm256_kernel, dim3(512), dim3(512), 0, stream,
                       Mw, xmt, x, inv, shift, out);
}

// Round 7
// 236.662 us; speedup vs baseline: 4.3796x; 4.3796x over previous
//
#include <hip/hip_runtime.h>
#include <hip/hip_bf16.h>

typedef __attribute__((ext_vector_type(8))) short bf16x8;
typedef __attribute__((ext_vector_type(4))) float f32x4;

#if defined(__has_builtin)
#if __has_builtin(__builtin_amdgcn_global_load_lds)
#define USE_GLOAD_LDS 1
#endif
#endif

__device__ __forceinline__ void gload_lds16(const void* g, void* ldsbase) {
#ifdef USE_GLOAD_LDS
    __builtin_amdgcn_global_load_lds(
        (__attribute__((address_space(1))) void*)(g),
        (__attribute__((address_space(3))) void*)(ldsbase), 16, 0, 0);
#endif
}

// ============ K1 early: pool (16384) + g_w transpose (512) + w_w cvt (256) + prepbias (32)
__global__ __launch_bounds__(256) void early_kernel(
        const float* __restrict__ x, float* __restrict__ xbar,
        const float* __restrict__ gw, const float* __restrict__ ww,
        __hip_bfloat16* __restrict__ gwt, __hip_bfloat16* __restrict__ wwb,
        const float* __restrict__ gb, const float* __restrict__ wb,
        const float* __restrict__ gamma, const float* __restrict__ beta,
        const float* __restrict__ mean, const float* __restrict__ var,
        float* __restrict__ inv, float* __restrict__ shift) {
    __shared__ float tile[32][33];
    int bid = blockIdx.x;
    int tid = threadIdx.x;
    if (bid < 16384) {
        // pool: xbar[(b*1024+c)*8+t] = mean_hw x
        int row = bid * 16 + (tid >> 4);
        int j = tid & 15;
        const float4* p = (const float4*)(x + (size_t)row * 128);
        float4 a = p[j * 2], b2 = p[j * 2 + 1];
        float s = a.x + a.y + a.z + a.w + b2.x + b2.y + b2.z + b2.w;
        s += __shfl_xor(s, 1); s += __shfl_xor(s, 2);
        s += __shfl_xor(s, 4); s += __shfl_xor(s, 8);
        if (j == 0) xbar[row] = s * (1.0f / 128.0f);
    } else if (bid < 16896) {
        // transpose+cvt a 32(ic) x 32(cin) tile of g_w [512][1024] -> gwt[1024][512]
        int b2 = bid - 16384;
        int icb = b2 >> 5, cb = b2 & 31;
        int r = tid >> 5, c = tid & 31;
        #pragma unroll
        for (int i = 0; i < 4; i++)
            tile[r + i * 8][c] = gw[(size_t)(icb * 32 + r + i * 8) * 1024 + cb * 32 + c];
        __syncthreads();
        #pragma unroll
        for (int i = 0; i < 4; i++) {
            int cin = cb * 32 + r + i * 8;
            gwt[(size_t)cin * 512 + icb * 32 + c] = __float2bfloat16(tile[c][r + i * 8]);
        }
    } else if (bid < 17152) {
        // convert w_w (1024x512 fp32) -> bf16
        int b2 = bid - 16896;
        size_t base = (size_t)b2 * 2048 + (size_t)tid * 8;
        const float4* src = (const float4*)(ww + base);
        float4 v0 = src[0], v1 = src[1];
        __hip_bfloat16 tmp[8];
        tmp[0] = __float2bfloat16(v0.x); tmp[1] = __float2bfloat16(v0.y);
        tmp[2] = __float2bfloat16(v0.z); tmp[3] = __float2bfloat16(v0.w);
        tmp[4] = __float2bfloat16(v1.x); tmp[5] = __float2bfloat16(v1.y);
        tmp[6] = __float2bfloat16(v1.z); tmp[7] = __float2bfloat16(v1.w);
        *(bf16x8*)(wwb + base) = *(const bf16x8*)tmp;
    } else {
        // prepbias: inv[c], shift[c] (wave-parallel dot over 512)
        int b2 = bid - 17152;
        int wv = tid >> 6, l = tid & 63;
        int c = b2 * 32 + wv * 8 + (l >> 3);
        int j = l & 7;
        const float* wr = ww + (size_t)c * 512;
        float acc = 0.0f;
        #pragma unroll 8
        for (int k = j; k < 512; k += 8) acc += wr[k] * gb[k];
        acc += __shfl_xor(acc, 1); acc += __shfl_xor(acc, 2); acc += __shfl_xor(acc, 4);
        if (j == 0) {
            float cb2 = wb[c] + acc;
            float iv = gamma[c] * rsqrtf(var[c] + 1e-5f);
            inv[c] = iv;
            shift[c] = cb2 * iv + beta[c] - mean[c] * iv;
        }
    }
}

// ============ K2 stage2: thetaphi (1024) + prepM via MFMA (64)
__global__ __launch_bounds__(256) void stage2_kernel(
        const float* __restrict__ xbar,
        const float* __restrict__ tw, const float* __restrict__ tb,
        const float* __restrict__ pw, const float* __restrict__ pb,
        float* __restrict__ theta, float* __restrict__ phi,
        const __hip_bfloat16* __restrict__ wwb,
        const __hip_bfloat16* __restrict__ gwt,
        __hip_bfloat16* __restrict__ M) {
    __shared__ __align__(16) char smem[32768];
    int bid = blockIdx.x;
    int tid = threadIdx.x;
    if (bid < 1024) {
        // theta/phi: [b][ic][t] = W @ xbar[b][:][t] + bias
        float* xs = (float*)smem;
        int which = bid & 1;
        int icc = (bid >> 1) & 15;
        int b = bid >> 5;
        const float* w = which ? pw : tw;
        const float* bias = which ? pb : tb;
        float* out = which ? phi : theta;
        for (int i = tid; i < 8192; i += 256) xs[i] = xbar[b * 8192 + i];
        __syncthreads();
        int icl = tid >> 3;
        int t = tid & 7;
        int ic = icc * 32 + icl;
        const float* wr = w + (size_t)ic * 1024;
        float acc = 0.0f;
        #pragma unroll 8
        for (int k = 0; k < 1024; k++) acc += wr[k] * xs[k * 8 + t];
        out[((size_t)b * 512 + ic) * 8 + t] = acc + bias[ic];
    } else {
        // prepM: M[c][cin] = sum_k wwb[c][k]*gwt[cin][k]   (128x128 MFMA tile)
        __hip_bfloat16* As = (__hip_bfloat16*)smem;
        __hip_bfloat16* Bs = (__hip_bfloat16*)(smem + 8192);
        int b2 = bid - 1024;
        int mb = b2 >> 3, nb = b2 & 7;
        int c0 = mb * 128, n0 = nb * 128;
        int w = tid >> 6, l = tid & 63;
        int wr = w >> 1, wc = w & 1;
        const __hip_bfloat16* Ab = wwb + (size_t)c0 * 512;
        const __hip_bfloat16* Bb = gwt + (size_t)n0 * 512;
        int arow = tid >> 2, akq = tid & 3;
        f32x4 acc[4][4] = {};
        for (int kk = 0; kk < 16; ++kk) {
            int k0 = kk * 32;
#ifdef USE_GLOAD_LDS
            gload_lds16(Ab + (size_t)arow * 512 + k0 + akq * 8,        (char*)As + w * 1024);
            gload_lds16(Ab + (size_t)(arow + 64) * 512 + k0 + akq * 8, (char*)As + 4096 + w * 1024);
            gload_lds16(Bb + (size_t)arow * 512 + k0 + akq * 8,        (char*)Bs + w * 1024);
            gload_lds16(Bb + (size_t)(arow + 64) * 512 + k0 + akq * 8, (char*)Bs + 4096 + w * 1024);
#else
            *(bf16x8*)((char*)As + (size_t)tid * 16)        = *(const bf16x8*)(Ab + (size_t)arow * 512 + k0 + akq * 8);
            *(bf16x8*)((char*)As + 4096 + (size_t)tid * 16) = *(const bf16x8*)(Ab + (size_t)(arow + 64) * 512 + k0 + akq * 8);
            *(bf16x8*)((char*)Bs + (size_t)tid * 16)        = *(const bf16x8*)(Bb + (size_t)arow * 512 + k0 + akq * 8);
            *(bf16x8*)((char*)Bs + 4096 + (size_t)tid * 16) = *(const bf16x8*)(Bb + (size_t)(arow + 64) * 512 + k0 + akq * 8);
#endif
            __syncthreads();
            const __hip_bfloat16* Ap = As + ((size_t)(wr * 64 + (l & 15)) * 32) + (l >> 4) * 8;
            const __hip_bfloat16* Bp = Bs + ((size_t)(wc * 64 + (l & 15)) * 32) + (l >> 4) * 8;
            bf16x8 af[4], bfr[4];
            #pragma unroll
            for (int m = 0; m < 4; m++) af[m] = *(const bf16x8*)(Ap + m * 16 * 32);
            #pragma unroll
            for (int n = 0; n < 4; n++) bfr[n] = *(const bf16x8*)(Bp + n * 16 * 32);
            #pragma unroll
            for (int m = 0; m < 4; m++)
                #pragma unroll
                for (int n = 0; n < 4; n++)
                    acc[m][n] = __builtin_amdgcn_mfma_f32_16x16x32_bf16(af[m], bfr[n], acc[m][n], 0, 0, 0);
            __syncthreads();
        }
        int col = l & 15, rg = l >> 4;
        #pragma unroll
        for (int m = 0; m < 4; m++)
            #pragma unroll
            for (int j = 0; j < 4; j++) {
                int gc = c0 + wr * 64 + m * 16 + rg * 4 + j;
                #pragma unroll
                for (int n = 0; n < 4; n++)
                    M[(size_t)gc * 1024 + n0 + wc * 64 + n * 16 + col] = __float2bfloat16(acc[m][n][j]);
            }
    }
}

// ------------------------------------------------------- attn[b][t][s] = softmax_s(theta.phi)
__global__ __launch_bounds__(64) void attn_kernel(const float* __restrict__ theta,
                                                  const float* __restrict__ phi,
                                                  float* __restrict__ attn) {
    __shared__ float th[4096], ph[4096];
    int b = blockIdx.x, lane = threadIdx.x;
    for (int i = lane; i < 4096; i += 64) {
        th[i] = theta[(size_t)b * 4096 + i];
        ph[i] = phi[(size_t)b * 4096 + i];
    }
    __syncthreads();
    int t = lane >> 3, s = lane & 7;
    float f = 0.0f;
    #pragma unroll 8
    for (int ic = 0; ic < 512; ic++) f += th[ic * 8 + t] * ph[ic * 8 + s];
    float m = f;
    m = fmaxf(m, __shfl_xor(m, 1));
    m = fmaxf(m, __shfl_xor(m, 2));
    m = fmaxf(m, __shfl_xor(m, 4));
    float e = __expf(f - m);
    float sum = e;
    sum += __shfl_xor(sum, 1); sum += __shfl_xor(sum, 2); sum += __shfl_xor(sum, 4);
    attn[b * 64 + lane] = e / sum;
}

// ------------- mix + transpose: xm_t[b][t*128+hw][c] (bf16) = sum_s attn[b][t][s]*x[b][c][s][hw]
__global__ __launch_bounds__(256) void mix_kernel(const float* __restrict__ x,
                                                  const float* __restrict__ attn,
                                                  __hip_bfloat16* __restrict__ xmt) {
    int orig = blockIdx.x;
    int wg = (orig & 7) * 64 + (orig >> 3);
    int b = wg >> 4;
    int hwg = wg & 15;                          // group of 8 hw positions
    __shared__ float at[64];
    __shared__ float xs[8][8][33];              // [s][h][ci], ci-dim padded to 33
    int tid = threadIdx.x;
    if (tid < 64) at[tid] = attn[b * 64 + tid];
    int ci = tid >> 3, s = tid & 7;             // staging role: 32 c x 8 s
    int h = tid >> 5, cq = tid & 31;            // compute role: 8 h x 32 c
    const float* xb = x + ((size_t)b << 20);
    __hip_bfloat16* ob = xmt + ((size_t)b << 20);
    for (int cc = 0; cc < 32; ++cc) {
        const float4* src = (const float4*)(xb + ((size_t)(cc * 32 + ci) * 8 + s) * 128 + hwg * 8);
        float4 v0 = src[0], v1 = src[1];
        __syncthreads();
        xs[s][0][ci] = v0.x; xs[s][1][ci] = v0.y; xs[s][2][ci] = v0.z; xs[s][3][ci] = v0.w;
        xs[s][4][ci] = v1.x; xs[s][5][ci] = v1.y; xs[s][6][ci] = v1.z; xs[s][7][ci] = v1.w;
        __syncthreads();
        float xr[8];
        #pragma unroll
        for (int ss = 0; ss < 8; ss++) xr[ss] = xs[ss][h][cq];
        #pragma unroll
        for (int t = 0; t < 8; t++) {
            float o = 0.0f;
            #pragma unroll
            for (int ss = 0; ss < 8; ss++) o += at[t * 8 + ss] * xr[ss];
            ob[(size_t)(t * 128 + hwg * 8 + h) * 1024 + cc * 32 + cq] = __float2bfloat16(o);
        }
    }
}

// ========== 256x256-tile / 8-wave GEMM, half-K(32) pipeline with counted vmcnt (R5) ==========
// out[b][c][n] = inv[c] * sum_k M[c][k]*xmt[b][n][k] + shift[c] + x[b][c][n]
// LDS: 4 half-buffers x (A 256x32 + B 256x32) bf16 = 128 KiB.
// 32 half-steps; step h: issue half h+3 (4 gloads/thread), ds_read+32 MFMA on half h,
// wait vmcnt(8) (= 2 halves outstanding), s_barrier. Loads get ~2.5 steps in flight.
// NOTE: 1 block/CU is register-capped (128 AGPR acc + ~108 VGPR); do NOT launch_bounds>2.
__global__ __launch_bounds__(512, 2) void gemm256_kernel(
        const __hip_bfloat16* __restrict__ Mw,    // [1024][1024]  (c, k)
        const __hip_bfloat16* __restrict__ xmt,   // [32][1024][1024] (n, k)
        const float* __restrict__ x,              // [32][1024][1024] (c, n)
        const float* __restrict__ inv, const float* __restrict__ shift,
        float* __restrict__ out) {
    __shared__ __align__(16) __hip_bfloat16 HBs[65536];        // 128 KiB = 4 x 32 KiB
    char* AH = (char*)HBs;
    const int BUFB = 32768;                                    // bytes per half-buffer

    int orig = blockIdx.x;
    int bid = (orig & 7) * 64 + (orig >> 3);      // XCD-chunked swizzle (512 % 8 == 0)
    int b = bid >> 4;
    int mb = (bid >> 2) & 3;
    int nb = bid & 3;
    int c0 = mb * 256, n0 = nb * 256;

    int tid = threadIdx.x;
    int w = tid >> 6, l = tid & 63;
    int wr = w >> 2, wc = w & 3;                  // 2 x 4 wave grid; wave out = 128(M) x 64(N)

    // ---- staging: lane l covers row w*16 + (l>>2), linear LDS slot l&3,
    //      global slot s = ((l&3) - ((l>>3)&3)) & 3  (inverse of slot' = (s + (row>>1))&3)
    int sgl = (((l & 3) - ((l >> 3) & 3)) & 3);
    const __hip_bfloat16* aS = Mw + (size_t)(c0 + w * 16 + (l >> 2)) * 1024 + sgl * 8;
    const __hip_bfloat16* bS = xmt + ((size_t)b << 20) + (size_t)(n0 + w * 16 + (l >> 2)) * 1024 + sgl * 8;
    int stBase = w * 1024;                        // byte base within half-region (wave slab)

    // ---- ds_read: slot = ((l>>4) + (((l&15)>>1)&3)) & 3, fragment adds 1024B (16 rows)
    int rdSlot = ((l >> 4) + (((l & 15) >> 1) & 3)) & 3;
    int aRdBase = (wr * 128 + (l & 15)) * 64 + rdSlot * 16;
    int bRdBase = 16384 + (wc * 64 + (l & 15)) * 64 + rdSlot * 16;

    f32x4 acc[8][4] = {};

    #define ISSUE(q3) do {                                                      \
        gload_lds16(aS,              AH + (q3) * BUFB + stBase);                \
        gload_lds16(aS + 128 * 1024, AH + (q3) * BUFB + stBase + 8192);         \
        gload_lds16(bS,              AH + (q3) * BUFB + 16384 + stBase);        \
        gload_lds16(bS + 128 * 1024, AH + (q3) * BUFB + 16384 + stBase + 8192); \
        aS += 32; bS += 32;                                                     \
    } while (0)

    #define V8 asm volatile("s_waitcnt vmcnt(8)" ::: "memory")
    #define V4 asm volatile("s_waitcnt vmcnt(4)" ::: "memory")
    #define V0 asm volatile("s_waitcnt vmcnt(0)" ::: "memory")

    #define HSTEP(q, DOISS, WAITM, LAST) do {                                   \
        if (DOISS) ISSUE(((q) + 3) & 3);                                        \
        const char* bufA = AH + (q) * BUFB;                                     \
        bf16x8 bfr[4];                                                          \
        _Pragma("unroll")                                                       \
        for (int n = 0; n < 4; ++n)                                             \
            bfr[n] = *(const bf16x8*)(bufA + bRdBase + n * 1024);               \
        __builtin_amdgcn_s_setprio(1);                                          \
        _Pragma("unroll")                                                       \
        for (int mi = 0; mi < 8; ++mi) {                                        \
            bf16x8 af = *(const bf16x8*)(bufA + aRdBase + mi * 1024);           \
            _Pragma("unroll")                                                   \
            for (int n = 0; n < 4; ++n)                                         \
                acc[mi][n] = __builtin_amdgcn_mfma_f32_16x16x32_bf16(           \
                    af, bfr[n], acc[mi][n], 0, 0, 0);                           \
        }                                                                       \
        __builtin_amdgcn_s_setprio(0);                                          \
        if (!LAST) {                                                            \
            WAITM;                                                              \
            __builtin_amdgcn_s_barrier();                                       \
            __builtin_amdgcn_sched_barrier(0);                                  \
        }                                                                       \
    } while (0)

    // prologue: issue halves 0,1,2 into bufs 0,1,2 (12 loads/thread)
    ISSUE(0); ISSUE(1); ISSUE(2);
    V8;                                           // half 0 landed (8 = halves 1,2 in flight)
    __builtin_amdgcn_s_barrier();
    __builtin_amdgcn_sched_barrier(0);

    // main: halves 0..27 (7 x 4), each issues half h+3
    #pragma unroll 1
    for (int t = 0; t < 7; ++t) {
        HSTEP(0, 1, V8, 0);
        HSTEP(1, 1, V8, 0);
        HSTEP(2, 1, V8, 0);
        HSTEP(3, 1, V8, 0);
    }
    HSTEP(0, 1, V8, 0);    // h=28, issues half 31 (last)
    HSTEP(1, 0, V4, 0);    // h=29
    HSTEP(2, 0, V0, 0);    // h=30
    HSTEP(3, 0, V0, 1);    // h=31 (no wait/barrier)

    #undef ISSUE
    #undef HSTEP
    #undef V8
    #undef V4
    #undef V0

    // epilogue: C/D layout col = l&15, row = (l>>4)*4 + j
    int col = l & 15, rg = l >> 4;
    const float* xb = x + ((size_t)b << 20);
    float* ob = out + ((size_t)b << 20);
    #pragma unroll
    for (int mi = 0; mi < 8; ++mi) {
        #pragma unroll
        for (int j = 0; j < 4; ++j) {
            int gc = c0 + wr * 128 + mi * 16 + rg * 4 + j;
            float iv = inv[gc], sh = shift[gc];
            size_t rowoff = (size_t)gc * 1024 + n0 + wc * 64 + col;
            #pragma unroll
            for (int n = 0; n < 4; ++n) {
                size_t idx = rowoff + n * 16;
                ob[idx] = acc[mi][n][j] * iv + sh + xb[idx];
            }
        }
    }
}

extern "C" void kernel_launch(void* const* d_in, const int* in_sizes, int n_in,
                              void* d_out, int out_size, void* d_ws, size_t ws_size,
                              hipStream_t stream) {
    const float* x    = (const float*)d_in[0];
    const float* g_w  = (const float*)d_in[1];
    const float* g_b  = (const float*)d_in[2];
    const float* th_w = (const float*)d_in[3];
    const float* th_b = (const float*)d_in[4];
    const float* ph_w = (const float*)d_in[5];
    const float* ph_b = (const float*)d_in[6];
    const float* w_w  = (const float*)d_in[7];
    const float* w_b  = (const float*)d_in[8];
    const float* gam  = (const float*)d_in[9];
    const float* bet  = (const float*)d_in[10];
    const float* mea  = (const float*)d_in[11];
    const float* var  = (const float*)d_in[12];
    float* out = (float*)d_out;
    char* ws = (char*)d_ws;

    __hip_bfloat16* xmt = (__hip_bfloat16*)ws;                    // 64 MiB (written by mix, late)
    __hip_bfloat16* Mw  = (__hip_bfloat16*)(ws + 67108864);       // 2 MiB
    float* xbar  = (float*)(ws + 69206016);                       // 1 MiB
    float* theta = (float*)(ws + 70254592);                       // 512 KiB
    float* phi   = (float*)(ws + 70778880);                       // 512 KiB
    float* attn  = (float*)(ws + 71303168);                       // 8 KiB
    float* inv   = (float*)(ws + 71311360);                       // 4 KiB
    float* shift = (float*)(ws + 71315456);                       // 4 KiB
    // gwt/wwb overlay the xmt region: consumed by stage2 (prepM) BEFORE mix writes xmt
    __hip_bfloat16* gwt = (__hip_bfloat16*)ws;                    // 1 MiB
    __hip_bfloat16* wwb = (__hip_bfloat16*)(ws + 1048576);        // 1 MiB

    hipLaunchKernelGGL(early_kernel, dim3(17184), dim3(256), 0, stream,
                       x, xbar, g_w, w_w, gwt, wwb,
                       g_b, w_b, gam, bet, mea, var, inv, shift);
    hipLaunchKernelGGL(stage2_kernel, dim3(1088), dim3(256), 0, stream,
                       xbar, th_w, th_b, ph_w, ph_b, theta, phi, wwb, gwt, Mw);
    hipLaunchKernelGGL(attn_kernel, dim3(32), dim3(64), 0, stream, theta, phi, attn);
    hipLaunchKernelGGL(mix_kernel, dim3(512), dim3(256), 0, stream, x, attn, xmt);
    hipLaunchKernelGGL(gemm256_kernel, dim3(512), dim3(512), 0, stream,
                       Mw, xmt, x, inv, shift, out);
}